// Round 9
// baseline (120.437 us; speedup 1.0000x reference)
//
#include <hip/hip_runtime.h>
#include <hip/hip_bf16.h>

// N=4,B=8,T=2,E=1024,H=16,D=64,S=2048,L=1024
#define NB_  32
#define T_   2
#define E_   1024
#define H_   16
#define D_   64
#define S_   2048
#define L_   1024
#define TOT_ (S_ + L_ + T_)   // 3074

#define PCH_  32              // prefix chunks per (n,h): 64 pos each
#define PLEN_ 64
#define PNT_  4               // prefix tiles (16 pos) per unit
#define CCH_  8               // cur chunks per (nb,h): 128 pos each
#define CLEN_ 128
#define CNT_  8               // cur tiles (16 pos) per unit

#define PFXU_ (4 * H_ * PCH_)   // 2048 prefix units
#define CURU_ (NB_ * H_ * CCH_) // 4096 cur units
#define GRID_ 2048              // persistent: 1 prefix + 2 cur units per block

#define LOG2E_ 1.4426950408889634f
#define QS_ (0.125f * LOG2E_)

#define GLOAD_LDS16(g, l) __builtin_amdgcn_global_load_lds( \
    (const __attribute__((address_space(1))) void*)(g), \
    (__attribute__((address_space(3))) void*)(l), 16, 0, 0)

// ---------------------------------------------------------------------------
// QKV: out[64][3072] = hidden[64][1024] @ Wcat^T + bias. (R8 proven)
// ---------------------------------------------------------------------------
__global__ __launch_bounds__(256) void qkv_kernel(
    const float* __restrict__ hidden,
    const float* __restrict__ Wq, const float* __restrict__ bq,
    const float* __restrict__ Wk, const float* __restrict__ bk,
    const float* __restrict__ Wv, const float* __restrict__ bv,
    float* __restrict__ qT,      // [1024][64]
    float* __restrict__ knew,    // [NB][H][T][D]
    float* __restrict__ vnew)
{
    __shared__ float ldsT[128 * 65];
    __shared__ float wlds[8 * 128];
    const int tid  = threadIdx.x;
    const int wave = tid >> 6;
    const int lane = tid & 63;
    const int eg0  = blockIdx.x * 8;
    const int mat  = eg0 >> 10;
    const int e0   = eg0 & 1023;
    int c0 = wave * 2;
    c0 = __builtin_amdgcn_readfirstlane(c0);

    const float* W    = (mat == 0) ? Wq : (mat == 1) ? Wk : Wv;
    const float* bias = (mat == 0) ? bq : (mat == 1) ? bk : bv;

    float aA0 = 0.f, aB0 = 0.f, aA1 = 0.f, aB1 = 0.f;

    for (int k0 = 0; k0 < 1024; k0 += 128) {
        __syncthreads();
        #pragma unroll
        for (int i = 0; i < 32; i++) {
            int f = i * 256 + tid;
            int r = f >> 7;
            int c = f & 127;
            ldsT[c * 65 + r] = hidden[r * 1024 + k0 + c];
        }
        {
            int wr = tid >> 5;
            int wc = (tid & 31) * 4;
            *reinterpret_cast<float4*>(&wlds[wr * 128 + wc]) =
                *reinterpret_cast<const float4*>(&W[(size_t)(e0 + wr) * 1024 + k0 + wc]);
        }
        __syncthreads();

        for (int kk = 0; kk < 128; kk += 4) {
            float h0 = ldsT[(kk + 0) * 65 + lane];
            float h1 = ldsT[(kk + 1) * 65 + lane];
            float h2 = ldsT[(kk + 2) * 65 + lane];
            float h3 = ldsT[(kk + 3) * 65 + lane];
            float4 w0 = *reinterpret_cast<const float4*>(&wlds[(c0 + 0) * 128 + kk]);
            float4 w1 = *reinterpret_cast<const float4*>(&wlds[(c0 + 1) * 128 + kk]);
            aA0 = fmaf(h0, w0.x, aA0); aA0 = fmaf(h1, w0.y, aA0);
            aB0 = fmaf(h2, w0.z, aB0); aB0 = fmaf(h3, w0.w, aB0);
            aA1 = fmaf(h0, w1.x, aA1); aA1 = fmaf(h1, w1.y, aA1);
            aB1 = fmaf(h2, w1.z, aB1); aB1 = fmaf(h3, w1.w, aB1);
        }
    }

    const int r = lane;
    #pragma unroll
    for (int j = 0; j < 2; j++) {
        int e_in = e0 + c0 + j;
        float val = ((j == 0) ? (aA0 + aB0) : (aA1 + aB1)) + bias[e_in];
        if (mat == 0) {
            qT[e_in * 64 + r] = val;
        } else {
            int nb = r >> 1, t = r & 1, h = e_in >> 6, d = e_in & 63;
            float* dst = (mat == 1) ? knew : vnew;
            dst[((nb * H_ + h) * T_ + t) * D_ + d] = val;
        }
    }
}

// ---------------------------------------------------------------------------
// Partial attention, persistent balanced: 2048 blocks (exactly 8/CU, no tail).
// Block = 1 prefix unit (64 pos, 4 tiles) + 2 cur units (128 pos, 8 tiles).
// Both paths: K/V streamed via global_load_lds, double-buffered 16-pos tiles
// (8 KB/tile, coalesced, no VGPR round-trip, drain only at the barrier).
// No-max exp2 softmax -> unnormalized (ctx,l) partials add in combine.
// ---------------------------------------------------------------------------
__global__ __launch_bounds__(256) void partial_kernel(
    const float* __restrict__ mask,   // [NB][TOT_]
    const float* __restrict__ pfx_k,  // [N][H][S][D]
    const float* __restrict__ pfx_v,
    const float* __restrict__ pk,     // [NB][H][L][D]
    const float* __restrict__ pv,
    const float* __restrict__ qT,     // [1024][64]
    const float* __restrict__ knew,   // [NB][H][T][D]
    const float* __restrict__ vnew,
    float* __restrict__ cur_ctx,      // [CURU_][2][64]
    float* __restrict__ cur_l,        // [CURU_][2]
    float* __restrict__ pfx_ctx,      // [PFXU_][16][64]
    float* __restrict__ pfx_l)        // [PFXU_][16]
{
    __shared__ float smem[4160];   // 2 stage buffers (2048 floats each: K|V);
                                   // reused as sred after a barrier
    const int tid = threadIdx.x;

    // ===================== phase 0: prefix unit v = blockIdx.x ==============
    {
        const int v     = blockIdx.x;
        const int n     = v >> 9;
        const int h     = (v >> 5) & 15;
        const int chunk = v & 31;
        const int wv    = tid >> 6;
        const int lane  = tid & 63;
        const int r     = lane & 15;          // row = beam*2 + t
        const int c     = lane >> 4;          // dim quarter

        float qreg[16];
        const float* qbase = qT + (h * 64 + c * 16) * 64 + (n * 16 + r);
        #pragma unroll
        for (int u = 0; u < 16; u++) qreg[u] = qbase[u * 64] * QS_;

        const size_t pos0 = (size_t)(n * H_ + h) * S_ + chunk * PLEN_;
        const float* kb = pfx_k + pos0 * D_;       // tile t: +t*1024
        const float* vb = pfx_v + pos0 * D_;
        const float* mrow = mask + (n * 8 + (r >> 1)) * TOT_ + chunk * PLEN_;

        float ctx[16];
        #pragma unroll
        for (int u = 0; u < 16; u++) ctx[u] = 0.f;
        float lsum = 0.f;

        GLOAD_LDS16(kb + tid * 4, &smem[tid * 4]);
        GLOAD_LDS16(vb + tid * 4, &smem[1024 + tid * 4]);

        #pragma unroll 1
        for (int t = 0; t < PNT_; t++) {
            const int bufo = (t & 1) * 2048;
            __syncthreads();   // tile t landed (vmcnt0 at barrier)

            float mreg[4];
            #pragma unroll
            for (int j = 0; j < 4; j++)
                mreg[j] = mrow[t * 16 + wv * 4 + j] * LOG2E_;

            if (t < PNT_ - 1) {
                const int nbo = ((t + 1) & 1) * 2048;
                const float* kn = kb + (size_t)(t + 1) * 1024;
                const float* vn = vb + (size_t)(t + 1) * 1024;
                GLOAD_LDS16(kn + tid * 4, &smem[nbo + tid * 4]);
                GLOAD_LDS16(vn + tid * 4, &smem[nbo + 1024 + tid * 4]);
            }

            #pragma unroll
            for (int j = 0; j < 4; j++) {
                const int pp = wv * 4 + j;
                const float4* kq = reinterpret_cast<const float4*>(
                    &smem[bufo + pp * 64 + c * 16]);
                float4 k0 = kq[0], k1 = kq[1], k2 = kq[2], k3 = kq[3];
                float sA = qreg[0]*k0.x;  sA = fmaf(qreg[1],k0.y,sA);
                sA = fmaf(qreg[2],k0.z,sA); sA = fmaf(qreg[3],k0.w,sA);
                float sB = qreg[4]*k1.x;  sB = fmaf(qreg[5],k1.y,sB);
                sB = fmaf(qreg[6],k1.z,sB); sB = fmaf(qreg[7],k1.w,sB);
                float sC = qreg[8]*k2.x;  sC = fmaf(qreg[9],k2.y,sC);
                sC = fmaf(qreg[10],k2.z,sC); sC = fmaf(qreg[11],k2.w,sC);
                float sD = qreg[12]*k3.x; sD = fmaf(qreg[13],k3.y,sD);
                sD = fmaf(qreg[14],k3.z,sD); sD = fmaf(qreg[15],k3.w,sD);
                float s = (sA + sB) + (sC + sD);
                s += __shfl_xor(s, 16, 64);
                s += __shfl_xor(s, 32, 64);
                float e = exp2f(s + mreg[j]);
                lsum += e;
                const float4* vq = reinterpret_cast<const float4*>(
                    &smem[bufo + 1024 + pp * 64 + c * 16]);
                float4 v0 = vq[0], v1 = vq[1], v2 = vq[2], v3 = vq[3];
                ctx[0]  += e * v0.x; ctx[1]  += e * v0.y; ctx[2]  += e * v0.z; ctx[3]  += e * v0.w;
                ctx[4]  += e * v1.x; ctx[5]  += e * v1.y; ctx[6]  += e * v1.z; ctx[7]  += e * v1.w;
                ctx[8]  += e * v2.x; ctx[9]  += e * v2.y; ctx[10] += e * v2.z; ctx[11] += e * v2.w;
                ctx[12] += e * v3.x; ctx[13] += e * v3.y; ctx[14] += e * v3.z; ctx[15] += e * v3.w;
            }
        }

        __syncthreads();   // stage buffers dead; reuse smem as sred
        const int base = wv * 1024 + r * 64 + c * 16;
        #pragma unroll
        for (int u = 0; u < 16; u += 4)
            *reinterpret_cast<float4*>(&smem[base + u]) =
                make_float4(ctx[u], ctx[u+1], ctx[u+2], ctx[u+3]);
        if (c == 0) smem[4096 + wv * 16 + r] = lsum;
        __syncthreads();

        const int pc = (n * H_ + h) * PCH_ + chunk;
        for (int e = tid; e < 1024; e += 256) {
            float s = smem[e] + smem[1024 + e] + smem[2048 + e] + smem[3072 + e];
            pfx_ctx[pc * 1024 + e] = s;
        }
        if (tid < 16) {
            float l = smem[4096 + tid] + smem[4096 + 16 + tid]
                    + smem[4096 + 32 + tid] + smem[4096 + 48 + tid];
            pfx_l[pc * 16 + tid] = l;
        }
    }

    // ================= phases 1,2: cur units u = bid, bid+2048 ==============
    #pragma unroll 1
    for (int kph = 0; kph < 2; kph++) {
        const int u     = blockIdx.x + kph * GRID_;   // 0..4095
        const int b     = u >> 3;                      // nb*16+h
        const int chunk = u & 7;
        const int nb    = b >> 4;
        const int h     = b & 15;
        const int g     = tid >> 4;     // group 0..15 = local position
        const int l16   = tid & 15;
        const int d0    = l16 * 4;

        float qf0[4], qf1[4];
        #pragma unroll
        for (int j = 0; j < 4; j++) {
            const float* qb = qT + (h * 64 + d0 + j) * 64 + nb * 2;
            qf0[j] = qb[0] * QS_;
            qf1[j] = qb[1] * QS_;
        }

        const float* kb = pk + ((nb * H_ + h) * (size_t)L_ + chunk * CLEN_) * D_;
        const float* vb = pv + ((nb * H_ + h) * (size_t)L_ + chunk * CLEN_) * D_;
        const float* mrow = mask + nb * TOT_ + S_ + chunk * CLEN_;

        // preload this unit's masks (group g, tiles 0..7)
        float mreg[8];
        #pragma unroll
        for (int t = 0; t < 8; t++) mreg[t] = mrow[t * 16 + g] * LOG2E_;

        float l0 = 0.f, l1 = 0.f;
        float a0[4] = {0.f,0.f,0.f,0.f};
        float a1[4] = {0.f,0.f,0.f,0.f};

        __syncthreads();   // previous phase done reading smem
        GLOAD_LDS16(kb + tid * 4, &smem[tid * 4]);
        GLOAD_LDS16(vb + tid * 4, &smem[1024 + tid * 4]);

        #pragma unroll 1
        for (int t = 0; t < CNT_; t++) {
            const int bufo = (t & 1) * 2048;
            __syncthreads();   // tile t landed

            if (t < CNT_ - 1) {
                const int nbo = ((t + 1) & 1) * 2048;
                const float* kn = kb + (size_t)(t + 1) * 1024;
                const float* vn = vb + (size_t)(t + 1) * 1024;
                GLOAD_LDS16(kn + tid * 4, &smem[nbo + tid * 4]);
                GLOAD_LDS16(vn + tid * 4, &smem[nbo + 1024 + tid * 4]);
            }

            float4 kf = *reinterpret_cast<const float4*>(&smem[bufo + g * 64 + d0]);
            float s0 = fmaf(qf0[0],kf.x, qf0[1]*kf.y) + fmaf(qf0[2],kf.z, qf0[3]*kf.w);
            float s1 = fmaf(qf1[0],kf.x, qf1[1]*kf.y) + fmaf(qf1[2],kf.z, qf1[3]*kf.w);
            #pragma unroll
            for (int off = 1; off < 16; off <<= 1) {
                s0 += __shfl_xor(s0, off, 64);
                s1 += __shfl_xor(s1, off, 64);
            }
            float e0 = exp2f(s0 + mreg[t]);
            float e1 = exp2f(s1 + mreg[t]);
            l0 += e0; l1 += e1;
            float4 vf = *reinterpret_cast<const float4*>(&smem[bufo + 1024 + g * 64 + d0]);
            a0[0] += e0 * vf.x; a0[1] += e0 * vf.y; a0[2] += e0 * vf.z; a0[3] += e0 * vf.w;
            a1[0] += e1 * vf.x; a1[1] += e1 * vf.y; a1[2] += e1 * vf.z; a1[3] += e1 * vf.w;
        }

        if (chunk == 7 && g < 2) {                // 2 new tokens
            const float* kn_b = knew + (nb * H_ + h) * (T_ * D_);
            const float* vn_b = vnew + (nb * H_ + h) * (T_ * D_);
            float4 kfn = *reinterpret_cast<const float4*>(kn_b + g * D_ + d0);
            float s0 = fmaf(qf0[0],kfn.x, qf0[1]*kfn.y) + fmaf(qf0[2],kfn.z, qf0[3]*kfn.w);
            float s1 = fmaf(qf1[0],kfn.x, qf1[1]*kfn.y) + fmaf(qf1[2],kfn.z, qf1[3]*kfn.w);
            #pragma unroll
            for (int off = 1; off < 16; off <<= 1) {
                s0 += __shfl_xor(s0, off, 64);
                s1 += __shfl_xor(s1, off, 64);
            }
            float mC = mask[nb * TOT_ + S_ + L_ + g] * LOG2E_;
            float e0 = exp2f(s0 + mC);
            float e1 = exp2f(s1 + mC);
            l0 += e0; l1 += e1;
            float4 vfn = *reinterpret_cast<const float4*>(vn_b + g * D_ + d0);
            a0[0] += e0 * vfn.x; a0[1] += e0 * vfn.y; a0[2] += e0 * vfn.z; a0[3] += e0 * vfn.w;
            a1[0] += e1 * vfn.x; a1[1] += e1 * vfn.y; a1[2] += e1 * vfn.z; a1[3] += e1 * vfn.w;
        }

        __syncthreads();   // stage buffers dead; reuse smem as sred
        #pragma unroll
        for (int j = 0; j < 4; j++) {
            smem[g * 128 + d0 + j]      = a0[j];
            smem[g * 128 + 64 + d0 + j] = a1[j];
        }
        if (l16 == 0) { smem[2048 + g * 2] = l0; smem[2048 + g * 2 + 1] = l1; }
        __syncthreads();

        if (tid < 128) {
            int t = tid >> 6, d = tid & 63;
            float s = 0.f, l = 0.f;
            for (int g2 = 0; g2 < 16; g2++) {
                s += smem[g2 * 128 + t * 64 + d];
                l += smem[2048 + g2 * 2 + t];
            }
            cur_ctx[(u * 2 + t) * 64 + d] = s;
            if (d == 0) cur_l[u * 2 + t] = l;
        }
        __syncthreads();   // done with smem before next phase's gloads
    }
}

// ---------------------------------------------------------------------------
// Combine: out = (sum of 8 cur + 32 prefix ctx partials) / (sum of l partials)
// ---------------------------------------------------------------------------
__global__ __launch_bounds__(256) void combine_kernel(
    const float* __restrict__ cur_ctx, const float* __restrict__ cur_l,
    const float* __restrict__ pfx_ctx, const float* __restrict__ pfx_l,
    float* __restrict__ out)
{
    const int row = blockIdx.x >> 2;      // nb*2+t
    const int qtr = blockIdx.x & 3;
    const int nb  = row >> 1, t = row & 1;
    const int n   = nb >> 3;
    const int r   = (nb & 7) * 2 + t;
    const int e   = qtr * 256 + threadIdx.x;   // h*64+d
    const int h   = e >> 6, d = e & 63;
    const int b   = nb * 16 + h;

    float val = 0.f, l = 0.f;
    #pragma unroll
    for (int ch = 0; ch < CCH_; ch++) {
        int cb = (b * CCH_ + ch);
        val += cur_ctx[(cb * 2 + t) * 64 + d];
        l   += cur_l[cb * 2 + t];
    }
    #pragma unroll
    for (int ch = 0; ch < PCH_; ch++) {
        int pc = (n * H_ + h) * PCH_ + ch;
        val += pfx_ctx[pc * 1024 + r * 64 + d];
        l   += pfx_l[pc * 16 + r];
    }
    out[row * 1024 + e] = val / l;
}

extern "C" void kernel_launch(void* const* d_in, const int* in_sizes, int n_in,
                              void* d_out, int out_size, void* d_ws, size_t ws_size,
                              hipStream_t stream) {
    const float* hidden = (const float*)d_in[0];
    const float* mask   = (const float*)d_in[1];
    const float* pfxk   = (const float*)d_in[2];
    const float* pfxv   = (const float*)d_in[3];
    const float* pk     = (const float*)d_in[4];
    const float* pv     = (const float*)d_in[5];
    const float* Wq     = (const float*)d_in[6];
    const float* bq     = (const float*)d_in[7];
    const float* Wk     = (const float*)d_in[8];
    const float* bk     = (const float*)d_in[9];
    const float* Wv     = (const float*)d_in[10];
    const float* bv     = (const float*)d_in[11];

    float* qT      = (float*)d_ws;             // 65536
    float* knew    = qT + 65536;               // 65536
    float* vnew    = knew + 65536;             // 65536
    float* cur_ctx = vnew + 65536;             // 4096*2*64 = 524288
    float* cur_l   = cur_ctx + 524288;         // 8192
    float* pfx_ctx = cur_l + 8192;             // 2048*1024 = 2097152
    float* pfx_l   = pfx_ctx + 2097152;        // 32768

    qkv_kernel<<<384, 256, 0, stream>>>(hidden, Wq, bq, Wk, bk, Wv, bv,
                                        qT, knew, vnew);
    partial_kernel<<<GRID_, 256, 0, stream>>>(
        mask, pfxk, pfxv, pk, pv, qT, knew, vnew,
        cur_ctx, cur_l, pfx_ctx, pfx_l);
    combine_kernel<<<256, 256, 0, stream>>>(cur_ctx, cur_l, pfx_ctx, pfx_l,
                                            (float*)d_out);
}

// Round 10
// 103.369 us; speedup vs baseline: 1.1651x; 1.1651x over previous
//
#include <hip/hip_runtime.h>
#include <hip/hip_bf16.h>

// N=4,B=8,T=2,E=1024,H=16,D=64,S=2048,L=1024
#define NB_  32
#define T_   2
#define E_   1024
#define H_   16
#define D_   64
#define S_   2048
#define L_   1024
#define TOT_ (S_ + L_ + T_)   // 3074

#define PCH_  16              // prefix chunks per (n,h): 128 pos each
#define PLEN_ (S_ / PCH_)     // 128
#define NT_   8               // tiles per prefix unit (16 pos each)
#define CCH_  8               // cur chunks per (nb,h): 128 pos each
#define CLEN_ (L_ / CCH_)     // 128

#define PFXBLK_ (4 * H_ * PCH_)   // 1024 prefix blocks
#define CURBLK_ (NB_ * H_ * CCH_) // 4096 cur blocks
#define PFXU_ PFXBLK_
#define CURU_ CURBLK_

#define LOG2E_ 1.4426950408889634f
#define QS_ (0.125f * LOG2E_)

#define GLOAD_LDS16(g, l) __builtin_amdgcn_global_load_lds( \
    (const __attribute__((address_space(1))) void*)(g), \
    (__attribute__((address_space(3))) void*)(l), 16, 0, 0)

// ---------------------------------------------------------------------------
// QKV: out[64][3072] = hidden[64][1024] @ Wcat^T + bias. (R8 proven)
// ---------------------------------------------------------------------------
__global__ __launch_bounds__(256) void qkv_kernel(
    const float* __restrict__ hidden,
    const float* __restrict__ Wq, const float* __restrict__ bq,
    const float* __restrict__ Wk, const float* __restrict__ bk,
    const float* __restrict__ Wv, const float* __restrict__ bv,
    float* __restrict__ qT,      // [1024][64]
    float* __restrict__ knew,    // [NB][H][T][D]
    float* __restrict__ vnew)
{
    __shared__ float ldsT[128 * 65];
    __shared__ float wlds[8 * 128];
    const int tid  = threadIdx.x;
    const int wave = tid >> 6;
    const int lane = tid & 63;
    const int eg0  = blockIdx.x * 8;
    const int mat  = eg0 >> 10;
    const int e0   = eg0 & 1023;
    int c0 = wave * 2;
    c0 = __builtin_amdgcn_readfirstlane(c0);

    const float* W    = (mat == 0) ? Wq : (mat == 1) ? Wk : Wv;
    const float* bias = (mat == 0) ? bq : (mat == 1) ? bk : bv;

    float aA0 = 0.f, aB0 = 0.f, aA1 = 0.f, aB1 = 0.f;

    for (int k0 = 0; k0 < 1024; k0 += 128) {
        __syncthreads();
        #pragma unroll
        for (int i = 0; i < 32; i++) {
            int f = i * 256 + tid;
            int r = f >> 7;
            int c = f & 127;
            ldsT[c * 65 + r] = hidden[r * 1024 + k0 + c];
        }
        {
            int wr = tid >> 5;
            int wc = (tid & 31) * 4;
            *reinterpret_cast<float4*>(&wlds[wr * 128 + wc]) =
                *reinterpret_cast<const float4*>(&W[(size_t)(e0 + wr) * 1024 + k0 + wc]);
        }
        __syncthreads();

        for (int kk = 0; kk < 128; kk += 4) {
            float h0 = ldsT[(kk + 0) * 65 + lane];
            float h1 = ldsT[(kk + 1) * 65 + lane];
            float h2 = ldsT[(kk + 2) * 65 + lane];
            float h3 = ldsT[(kk + 3) * 65 + lane];
            float4 w0 = *reinterpret_cast<const float4*>(&wlds[(c0 + 0) * 128 + kk]);
            float4 w1 = *reinterpret_cast<const float4*>(&wlds[(c0 + 1) * 128 + kk]);
            aA0 = fmaf(h0, w0.x, aA0); aA0 = fmaf(h1, w0.y, aA0);
            aB0 = fmaf(h2, w0.z, aB0); aB0 = fmaf(h3, w0.w, aB0);
            aA1 = fmaf(h0, w1.x, aA1); aA1 = fmaf(h1, w1.y, aA1);
            aB1 = fmaf(h2, w1.z, aB1); aB1 = fmaf(h3, w1.w, aB1);
        }
    }

    const int r = lane;
    #pragma unroll
    for (int j = 0; j < 2; j++) {
        int e_in = e0 + c0 + j;
        float val = ((j == 0) ? (aA0 + aB0) : (aA1 + aB1)) + bias[e_in];
        if (mat == 0) {
            qT[e_in * 64 + r] = val;
        } else {
            int nb = r >> 1, t = r & 1, h = e_in >> 6, d = e_in & 63;
            float* dst = (mat == 1) ? knew : vnew;
            dst[((nb * H_ + h) * T_ + t) * D_ + d] = val;
        }
    }
}

// ---------------------------------------------------------------------------
// Partial attention. 5120 one-shot blocks x 256 thr, prefix blocks first.
//  [0,1024):    prefix (n,h,chunk16): 128 pos in 8 LDS-staged tiles of 16
//               via double-buffered global_load_lds (16-way broadcast reuse).
//  [1024,5120): cur (nb,h,chunk8): 128 pos, register stream with DEPTH-8
//               pipeline: all 16 K/V float4 loads of the unit issued before
//               the first compute stage (16KB/wave in flight; HBM latency
//               paid once per unit, not 8x). No LDS staging: cur K/V has
//               zero reuse, R9 proved LDS tiles regress here.
// No-max exp2 softmax -> unnormalized (ctx,l) partials add in combine.
// ---------------------------------------------------------------------------
__global__ __launch_bounds__(256) void partial_kernel(
    const float* __restrict__ mask,   // [NB][TOT_]
    const float* __restrict__ pfx_k,  // [N][H][S][D]
    const float* __restrict__ pfx_v,
    const float* __restrict__ pk,     // [NB][H][L][D]
    const float* __restrict__ pv,
    const float* __restrict__ qT,     // [1024][64]
    const float* __restrict__ knew,   // [NB][H][T][D]
    const float* __restrict__ vnew,
    float* __restrict__ cur_ctx,      // [CURU_][2][64]
    float* __restrict__ cur_l,        // [CURU_][2]
    float* __restrict__ pfx_ctx,      // [PFXU_][16][64]
    float* __restrict__ pfx_l)        // [PFXU_][16]
{
    __shared__ float smem[4160];   // prefix: 2 stage buffers (2048 each, K|V);
                                   // both paths: sred reduction at the end
    const int tid = threadIdx.x;

    if (blockIdx.x < PFXBLK_) {
        // ================= prefix path (R8 proven) =================
        const int v     = blockIdx.x;
        const int n     = v >> 8;             // /(H_*PCH_)=256
        const int h     = (v >> 4) & 15;
        const int chunk = v & 15;
        const int wv    = tid >> 6;
        const int lane  = tid & 63;
        const int r     = lane & 15;          // row = beam*2 + t
        const int c     = lane >> 4;          // dim quarter

        float qreg[16];
        const float* qbase = qT + (h * 64 + c * 16) * 64 + (n * 16 + r);
        #pragma unroll
        for (int u = 0; u < 16; u++) qreg[u] = qbase[u * 64] * QS_;

        const size_t pos0 = (size_t)(n * H_ + h) * S_ + chunk * PLEN_;
        const float* kb = pfx_k + pos0 * D_;           // tile t: +t*16*64
        const float* vb = pfx_v + pos0 * D_;
        const float* mrow = mask + (n * 8 + (r >> 1)) * TOT_ + chunk * PLEN_;

        float ctx[16];
        #pragma unroll
        for (int u = 0; u < 16; u++) ctx[u] = 0.f;
        float lsum = 0.f;

        // stage tile 0 into buffer 0
        GLOAD_LDS16(kb + tid * 4, &smem[tid * 4]);
        GLOAD_LDS16(vb + tid * 4, &smem[1024 + tid * 4]);

        #pragma unroll 1
        for (int t = 0; t < NT_; t++) {
            const int bufo = (t & 1) * 2048;
            __syncthreads();   // drains this tile's gloads (vmcnt0 at barrier)

            // preload this tile's mask values (older than next gloads)
            float mreg[4];
            #pragma unroll
            for (int j = 0; j < 4; j++)
                mreg[j] = mrow[t * 16 + wv * 4 + j] * LOG2E_;

            if (t < NT_ - 1) {   // issue next tile into other buffer
                const int nbo = ((t + 1) & 1) * 2048;
                const float* kn = kb + (size_t)(t + 1) * 16 * 64;
                const float* vn = vb + (size_t)(t + 1) * 16 * 64;
                GLOAD_LDS16(kn + tid * 4, &smem[nbo + tid * 4]);
                GLOAD_LDS16(vn + tid * 4, &smem[nbo + 1024 + tid * 4]);
            }

            // compute 4 positions per wave from LDS
            #pragma unroll
            for (int j = 0; j < 4; j++) {
                const int pp = wv * 4 + j;
                const float4* kq = reinterpret_cast<const float4*>(
                    &smem[bufo + pp * 64 + c * 16]);
                float4 k0 = kq[0], k1 = kq[1], k2 = kq[2], k3 = kq[3];
                float sA = qreg[0]*k0.x;  sA = fmaf(qreg[1],k0.y,sA);
                sA = fmaf(qreg[2],k0.z,sA); sA = fmaf(qreg[3],k0.w,sA);
                float sB = qreg[4]*k1.x;  sB = fmaf(qreg[5],k1.y,sB);
                sB = fmaf(qreg[6],k1.z,sB); sB = fmaf(qreg[7],k1.w,sB);
                float sC = qreg[8]*k2.x;  sC = fmaf(qreg[9],k2.y,sC);
                sC = fmaf(qreg[10],k2.z,sC); sC = fmaf(qreg[11],k2.w,sC);
                float sD = qreg[12]*k3.x; sD = fmaf(qreg[13],k3.y,sD);
                sD = fmaf(qreg[14],k3.z,sD); sD = fmaf(qreg[15],k3.w,sD);
                float s = (sA + sB) + (sC + sD);
                s += __shfl_xor(s, 16, 64);
                s += __shfl_xor(s, 32, 64);
                float e = exp2f(s + mreg[j]);
                lsum += e;
                const float4* vq = reinterpret_cast<const float4*>(
                    &smem[bufo + 1024 + pp * 64 + c * 16]);
                float4 v0 = vq[0], v1 = vq[1], v2 = vq[2], v3 = vq[3];
                ctx[0]  += e * v0.x; ctx[1]  += e * v0.y; ctx[2]  += e * v0.z; ctx[3]  += e * v0.w;
                ctx[4]  += e * v1.x; ctx[5]  += e * v1.y; ctx[6]  += e * v1.z; ctx[7]  += e * v1.w;
                ctx[8]  += e * v2.x; ctx[9]  += e * v2.y; ctx[10] += e * v2.z; ctx[11] += e * v2.w;
                ctx[12] += e * v3.x; ctx[13] += e * v3.y; ctx[14] += e * v3.z; ctx[15] += e * v3.w;
            }
        }

        __syncthreads();   // stage buffers dead; reuse smem as sred
        const int base = wv * 1024 + r * 64 + c * 16;
        #pragma unroll
        for (int u = 0; u < 16; u += 4)
            *reinterpret_cast<float4*>(&smem[base + u]) =
                make_float4(ctx[u], ctx[u+1], ctx[u+2], ctx[u+3]);
        if (c == 0) smem[4096 + wv * 16 + r] = lsum;
        __syncthreads();

        const int pc = (n * H_ + h) * PCH_ + chunk;
        for (int e = tid; e < 1024; e += 256) {
            float s = smem[e] + smem[1024 + e] + smem[2048 + e] + smem[3072 + e];
            pfx_ctx[pc * 1024 + e] = s;
        }
        if (tid < 16) {
            float l = smem[4096 + tid] + smem[4096 + 16 + tid]
                    + smem[4096 + 32 + tid] + smem[4096 + 48 + tid];
            pfx_l[pc * 16 + tid] = l;
        }
    } else {
        // ================= cur path: depth-8 register pipeline =============
        const int u     = blockIdx.x - PFXBLK_;   // 0..4095
        const int b     = u >> 3;                  // nb*16+h
        const int chunk = u & 7;
        const int nb    = b >> 4;
        const int h     = b & 15;
        const int g     = tid >> 4;     // group 0..15
        const int l16   = tid & 15;
        const int d0    = l16 * 4;

        float qf0[4], qf1[4];
        #pragma unroll
        for (int j = 0; j < 4; j++) {
            const float* qb = qT + (h * 64 + d0 + j) * 64 + nb * 2;
            qf0[j] = qb[0] * QS_;
            qf1[j] = qb[1] * QS_;
        }

        const float* pk_b = pk + ((nb * H_ + h) * (size_t)L_) * D_;
        const float* pv_b = pv + ((nb * H_ + h) * (size_t)L_) * D_;
        const float* mrow = mask + nb * TOT_ + S_;
        const int p0 = chunk * CLEN_ + g;

        // masks first (their vmcnt retires before the big K/V batch)
        float mreg[8];
        #pragma unroll
        for (int i = 0; i < 8; i++) mreg[i] = mrow[p0 + i * 16] * LOG2E_;

        // issue ALL unit loads: 16 float4/thread in flight (static arrays)
        float4 kf[8], vf[8];
        #pragma unroll
        for (int i = 0; i < 8; i++) {
            kf[i] = *reinterpret_cast<const float4*>(pk_b + (size_t)(p0 + i * 16) * D_ + d0);
            vf[i] = *reinterpret_cast<const float4*>(pv_b + (size_t)(p0 + i * 16) * D_ + d0);
        }

        float l0 = 0.f, l1 = 0.f;
        float a0[4] = {0.f,0.f,0.f,0.f};
        float a1[4] = {0.f,0.f,0.f,0.f};

        #pragma unroll
        for (int i = 0; i < 8; i++) {
            float s0 = fmaf(qf0[0],kf[i].x, qf0[1]*kf[i].y) + fmaf(qf0[2],kf[i].z, qf0[3]*kf[i].w);
            float s1 = fmaf(qf1[0],kf[i].x, qf1[1]*kf[i].y) + fmaf(qf1[2],kf[i].z, qf1[3]*kf[i].w);
            #pragma unroll
            for (int off = 1; off < 16; off <<= 1) {
                s0 += __shfl_xor(s0, off, 64);
                s1 += __shfl_xor(s1, off, 64);
            }
            float e0 = exp2f(s0 + mreg[i]);
            float e1 = exp2f(s1 + mreg[i]);
            l0 += e0; l1 += e1;
            a0[0] += e0 * vf[i].x; a0[1] += e0 * vf[i].y; a0[2] += e0 * vf[i].z; a0[3] += e0 * vf[i].w;
            a1[0] += e1 * vf[i].x; a1[1] += e1 * vf[i].y; a1[2] += e1 * vf[i].z; a1[3] += e1 * vf[i].w;
        }

        if (chunk == 7 && g < 2) {                // 2 new tokens
            const float* kn_b = knew + (nb * H_ + h) * (T_ * D_);
            const float* vn_b = vnew + (nb * H_ + h) * (T_ * D_);
            float4 kfn = *reinterpret_cast<const float4*>(kn_b + g * D_ + d0);
            float s0 = fmaf(qf0[0],kfn.x, qf0[1]*kfn.y) + fmaf(qf0[2],kfn.z, qf0[3]*kfn.w);
            float s1 = fmaf(qf1[0],kfn.x, qf1[1]*kfn.y) + fmaf(qf1[2],kfn.z, qf1[3]*kfn.w);
            #pragma unroll
            for (int off = 1; off < 16; off <<= 1) {
                s0 += __shfl_xor(s0, off, 64);
                s1 += __shfl_xor(s1, off, 64);
            }
            float mC = mrow[L_ + g] * LOG2E_;
            float e0 = exp2f(s0 + mC);
            float e1 = exp2f(s1 + mC);
            l0 += e0; l1 += e1;
            float4 vfn = *reinterpret_cast<const float4*>(vn_b + g * D_ + d0);
            a0[0] += e0 * vfn.x; a0[1] += e0 * vfn.y; a0[2] += e0 * vfn.z; a0[3] += e0 * vfn.w;
            a1[0] += e1 * vfn.x; a1[1] += e1 * vfn.y; a1[2] += e1 * vfn.z; a1[3] += e1 * vfn.w;
        }

        #pragma unroll
        for (int j = 0; j < 4; j++) {
            smem[g * 128 + d0 + j]      = a0[j];
            smem[g * 128 + 64 + d0 + j] = a1[j];
        }
        if (l16 == 0) { smem[2048 + g * 2] = l0; smem[2048 + g * 2 + 1] = l1; }
        __syncthreads();

        if (tid < 128) {
            int t = tid >> 6, d = tid & 63;
            float s = 0.f, l = 0.f;
            for (int g2 = 0; g2 < 16; g2++) {
                s += smem[g2 * 128 + t * 64 + d];
                l += smem[2048 + g2 * 2 + t];
            }
            cur_ctx[(u * 2 + t) * 64 + d] = s;
            if (d == 0) cur_l[u * 2 + t] = l;
        }
    }
}

// ---------------------------------------------------------------------------
// Combine: out = (sum of 8 cur + 16 prefix ctx partials) / (sum of l partials)
// ---------------------------------------------------------------------------
__global__ __launch_bounds__(256) void combine_kernel(
    const float* __restrict__ cur_ctx, const float* __restrict__ cur_l,
    const float* __restrict__ pfx_ctx, const float* __restrict__ pfx_l,
    float* __restrict__ out)
{
    const int row = blockIdx.x >> 2;      // nb*2+t
    const int qtr = blockIdx.x & 3;
    const int nb  = row >> 1, t = row & 1;
    const int n   = nb >> 3;
    const int r   = (nb & 7) * 2 + t;
    const int e   = qtr * 256 + threadIdx.x;   // h*64+d
    const int h   = e >> 6, d = e & 63;
    const int b   = nb * 16 + h;

    float val = 0.f, l = 0.f;
    #pragma unroll
    for (int ch = 0; ch < CCH_; ch++) {
        int cb = (b * CCH_ + ch);
        val += cur_ctx[(cb * 2 + t) * 64 + d];
        l   += cur_l[cb * 2 + t];
    }
    #pragma unroll
    for (int ch = 0; ch < PCH_; ch++) {
        int pc = (n * H_ + h) * PCH_ + ch;
        val += pfx_ctx[pc * 1024 + r * 64 + d];
        l   += pfx_l[pc * 16 + r];
    }
    out[row * 1024 + e] = val / l;
}

extern "C" void kernel_launch(void* const* d_in, const int* in_sizes, int n_in,
                              void* d_out, int out_size, void* d_ws, size_t ws_size,
                              hipStream_t stream) {
    const float* hidden = (const float*)d_in[0];
    const float* mask   = (const float*)d_in[1];
    const float* pfxk   = (const float*)d_in[2];
    const float* pfxv   = (const float*)d_in[3];
    const float* pk     = (const float*)d_in[4];
    const float* pv     = (const float*)d_in[5];
    const float* Wq     = (const float*)d_in[6];
    const float* bq     = (const float*)d_in[7];
    const float* Wk     = (const float*)d_in[8];
    const float* bk     = (const float*)d_in[9];
    const float* Wv     = (const float*)d_in[10];
    const float* bv     = (const float*)d_in[11];

    float* qT      = (float*)d_ws;             // 65536
    float* knew    = qT + 65536;               // 65536
    float* vnew    = knew + 65536;             // 65536
    float* cur_ctx = vnew + 65536;             // 4096*2*64 = 524288
    float* cur_l   = cur_ctx + 524288;         // 8192
    float* pfx_ctx = cur_l + 8192;             // 1024*1024 = 1048576
    float* pfx_l   = pfx_ctx + 1048576;        // 16384

    qkv_kernel<<<384, 256, 0, stream>>>(hidden, Wq, bq, Wk, bk, Wv, bv,
                                        qT, knew, vnew);
    partial_kernel<<<PFXBLK_ + CURBLK_, 256, 0, stream>>>(
        mask, pfxk, pfxv, pk, pv, qT, knew, vnew,
        cur_ctx, cur_l, pfx_ctx, pfx_l);
    combine_kernel<<<256, 256, 0, stream>>>(cur_ctx, cur_l, pfx_ctx, pfx_l,
                                            (float*)d_out);
}